// Round 4
// baseline (612.297 us; speedup 1.0000x reference)
//
#include <hip/hip_runtime.h>
#include <hip/hip_fp16.h>
#include <hip/hip_cooperative_groups.h>

namespace cg = cooperative_groups;

#define EPS 1e-5f
#define ABITS 8           // 256 nodes per target-bucket
#define NBKT_MAX 512      // allocated bucket-meta slots (>= ceil(N/256))
#define ACHUNK 2048       // edges per block-iteration in bucket pass A
#define BCAP 4096         // tmp capacity per bucket (avg ~3072, ~18 sigma margin)
#define BCSR 6144         // padded csr capacity per bucket (<= BCAP + 256*7)
#define CSHIFT 13         // src-chunk = src >> 13 (1 MB of t per chunk)
#define NCHUNK 16
#define SMEM_BYTES 34816  // max phase demand = gemm0 (2 x 64x136 fp16 tiles)
// tmp entry packing: (dstOff << 17) | src  — requires N <= 131072 (N=100000 ok)

typedef _Float16 half8 __attribute__((ext_vector_type(8)));
typedef float floatx4 __attribute__((ext_vector_type(4)));

struct GcnParams {
    const float* x; const int* ei;
    const float* w0; const float* w1; const float* w2;
    const float* biases; const float* gamma; const float* beta;
    const float* rmean; const float* rvar;
    const float* cls_w; const float* cls_b;
    float* out;
    float* dinv; int2* rowse; int* bucket_fill; int* perm;
    unsigned* tmp; int* csr; __half* tA; __half* tB;
    int N, E, na, nbuckets, gtiles, atiles;
};

// ---------------- phase 1: edge bucketing (grid-stride over chunks) ----------------

__device__ __forceinline__ void bucketA_body(char* smem, const GcnParams& P, int chunk) {
    int2* edg  = (int2*)smem;                 // 16 KB
    int* hist  = (int*)(smem + 16384);        // 2 KB
    int* lbase = (int*)(smem + 18432);        // 2 KB
    int* lcur  = (int*)(smem + 20480);        // 2 KB
    int t = threadIdx.x;
    for (int i = t; i < NBKT_MAX; i += 256) { hist[i] = 0; lcur[i] = 0; }
    __syncthreads();
    int e0 = chunk * ACHUNK;
    int e1 = e0 + ACHUNK; if (e1 > P.E) e1 = P.E;
    int ne = e1 - e0;
    for (int idx = t; idx < ne; idx += 256) {
        int r = P.ei[e0 + idx], c = P.ei[P.E + e0 + idx];
        edg[idx] = make_int2(r, c);
        atomicAdd(&hist[c >> ABITS], 1);
    }
    __syncthreads();
    for (int i = t; i < NBKT_MAX; i += 256) {
        int h = hist[i];
        if (h) lbase[i] = atomicAdd(&P.bucket_fill[i], h);
    }
    __syncthreads();
    for (int idx = t; idx < ne; idx += 256) {
        int2 e = edg[idx];
        int b = e.y >> ABITS;
        int l = atomicAdd(&lcur[b], 1);
        P.tmp[(size_t)b * BCAP + lbase[b] + l] = ((unsigned)(e.y & 255) << 17) | (unsigned)e.x;
    }
    __syncthreads();   // LDS reuse across grid-stride iterations
}

// ---------------- phase 2: per-bucket CSR build + window-local class sort ----------------

__device__ __forceinline__ void bucketB_body(char* smem, const GcnParams& P, int b) {
    unsigned* edg = (unsigned*)smem;          // 16 KB (packed)
    int* cnt2   = (int*)(smem + 16384);       // 16 KB: counts -> seg cursors
    int* wsum   = (int*)(smem + 32768);
    int* ccnt   = (int*)(smem + 32784);
    int* cbaseS = (int*)(smem + 32848);
    int t = threadIdx.x;
    int lane = t & 63, wv = t >> 6;
    int n0 = b << ABITS;
    int cntN = P.N - n0; if (cntN > 256) cntN = 256;
    int ne = P.bucket_fill[b]; if (ne > BCAP) ne = BCAP;
    int base = b * BCAP;
    int cbase = b * BCSR;
    if (t < 16) ccnt[t] = 0;
    for (int i = t; i < 256 * NCHUNK; i += 256) cnt2[i] = 0;
    for (int idx = t; idx < ne; idx += 256) edg[idx] = P.tmp[(size_t)base + idx];
    __syncthreads();
    for (int idx = t; idx < ne; idx += 256) {
        unsigned e = edg[idx];
        int dstOff = e >> 17, src = e & 0x1FFFF;
        atomicAdd(&cnt2[dstOff * NCHUNK + (src >> CSHIFT)], 1);
    }
    __syncthreads();
    int c0 = 0;
#pragma unroll
    for (int c = 0; c < NCHUNK; ++c) c0 += cnt2[t * NCHUNK + c];
    // degree-class rank within this bucket (iterations in agg = ceil(deg/8))
    int k0c = (c0 + 7) >> 3; if (k0c > 15) k0c = 15;
    int rank0 = 0;
    if (t < cntN) rank0 = atomicAdd(&ccnt[k0c], 1);
    int p0 = (c0 + 7) & ~7;                   // padded length
    // inclusive wave-shfl scan of p0 across 256 threads
    int v = p0;
#pragma unroll
    for (int off = 1; off < 64; off <<= 1) {
        int u = __shfl_up(v, off);
        if (lane >= off) v += u;
    }
    if (lane == 63) wsum[wv] = v;
    __syncthreads();
    int addv = 0;
    for (int j = 0; j < wv; ++j) addv += wsum[j];
    int excl = v + addv - p0;
    int st0 = cbase + excl;
    if (t < cntN) {
        P.rowse[n0 + t] = make_int2(st0, st0 + c0);
        P.dinv[n0 + t] = rsqrtf((float)(c0 + 1));
        // pads: fill [start+deg, start+pdeg) with own node index (self row, L2-hot)
        for (int j = c0; j < p0; ++j) P.csr[st0 + j] = n0 + t;
    }
    // counts -> per-(node,chunk) segment cursors
    int run = st0;
#pragma unroll
    for (int c = 0; c < NCHUNK; ++c) {
        int vv = cnt2[t * NCHUNK + c];
        cnt2[t * NCHUNK + c] = run;
        run += vv;
    }
    // class-base prefix (16 classes) for the window-local sort
    if (t < 16) {
        int sacc = 0;
        for (int j = 0; j < t; ++j) sacc += ccnt[j];
        cbaseS[t] = sacc;
    }
    __syncthreads();
    if (t < cntN) P.perm[n0 + cbaseS[k0c] + rank0] = n0 + t;
    for (int idx = t; idx < ne; idx += 256) {
        unsigned e = edg[idx];
        int dstOff = e >> 17, src = e & 0x1FFFF;
        int key = dstOff * NCHUNK + (src >> CSHIFT);
        int pos = atomicAdd(&cnt2[key], 1);
        P.csr[pos] = src;
    }
    __syncthreads();   // LDS reuse across grid-stride iterations
}

// ---------------- phase 3: layer-0 GEMM [N,128]@[128,64] -> dinv * h (fp16) ----------------
// W staged to LDS ONCE per block for the whole phase (was: once per 64-row tile).

__device__ __forceinline__ void gemm_phase(char* smem, const GcnParams& P, int bid, int gdim) {
    const int K = 128, KP = 136;
    _Float16* Ah = (_Float16*)smem;               // 17408 B
    _Float16* Wt = (_Float16*)(smem + 17408);     // 17408 B
    int tid = threadIdx.x;
    for (int idx = tid; idx < K * 64; idx += 256) {
        int k = idx >> 6, c = idx & 63;
        Wt[c * KP + k] = (_Float16)P.w0[idx];
    }
    __syncthreads();
    int w = tid >> 6, lane = tid & 63;
    int m = lane & 15, quad = lane >> 4;
    for (int tile = bid; tile < P.gtiles; tile += gdim) {
        int row0 = tile * 64;
        const float* Ab = P.x + (size_t)row0 * K;
        int limit = (P.N - row0) * K; if (limit > 64 * K) limit = 64 * K;
        for (int f = tid * 4; f < 64 * K; f += 1024) {
            float4 v = make_float4(0.f, 0.f, 0.f, 0.f);
            if (f + 3 < limit) {
                v = *(const float4*)(Ab + f);
            } else {
                if (f + 0 < limit) v.x = Ab[f + 0];
                if (f + 1 < limit) v.y = Ab[f + 1];
                if (f + 2 < limit) v.z = Ab[f + 2];
            }
            int row = f >> 7, k = f & 127;
            _Float16* dst = Ah + row * KP + k;
            dst[0] = (_Float16)v.x; dst[1] = (_Float16)v.y;
            dst[2] = (_Float16)v.z; dst[3] = (_Float16)v.w;
        }
        __syncthreads();
        const _Float16* Aw = Ah + (size_t)(w * 16 + m) * KP + quad * 8;
        const _Float16* Bw = Wt + (size_t)m * KP + quad * 8;
        floatx4 acc0 = {0.f, 0.f, 0.f, 0.f}, acc1 = acc0, acc2 = acc0, acc3 = acc0;
#pragma unroll
        for (int k0 = 0; k0 < K; k0 += 32) {
            half8 a  = *(const half8*)(Aw + k0);
            half8 b0 = *(const half8*)(Bw + 0 * 16 * KP + k0);
            half8 b1 = *(const half8*)(Bw + 1 * 16 * KP + k0);
            half8 b2 = *(const half8*)(Bw + 2 * 16 * KP + k0);
            half8 b3 = *(const half8*)(Bw + 3 * 16 * KP + k0);
            acc0 = __builtin_amdgcn_mfma_f32_16x16x32_f16(a, b0, acc0, 0, 0, 0);
            acc1 = __builtin_amdgcn_mfma_f32_16x16x32_f16(a, b1, acc1, 0, 0, 0);
            acc2 = __builtin_amdgcn_mfma_f32_16x16x32_f16(a, b2, acc2, 0, 0, 0);
            acc3 = __builtin_amdgcn_mfma_f32_16x16x32_f16(a, b3, acc3, 0, 0, 0);
        }
        int rbase = row0 + w * 16 + quad * 4;
#pragma unroll
        for (int r = 0; r < 4; ++r) {
            int row = rbase + r;
            if (row < P.N) {
                float dv = P.dinv[row];
                __half* o = P.tA + (size_t)row * 64 + m;
                o[0]  = __float2half(acc0[r] * dv);
                o[16] = __float2half(acc1[r] * dv);
                o[32] = __float2half(acc2[r] * dv);
                o[48] = __float2half(acc3[r] * dv);
            }
        }
        __syncthreads();   // protect Ah before next tile overwrites
    }
}

// ---------------- aggregation core (unchanged from R3) ----------------

__device__ __forceinline__ void agg_add8(float4& lo, float4& hi, uint4 raw) {
    float2 p0 = __half22float2(*(const __half2*)&raw.x);
    float2 p1 = __half22float2(*(const __half2*)&raw.y);
    float2 p2 = __half22float2(*(const __half2*)&raw.z);
    float2 p3 = __half22float2(*(const __half2*)&raw.w);
    lo.x += p0.x; lo.y += p0.y; lo.z += p1.x; lo.w += p1.y;
    hi.x += p2.x; hi.y += p2.y; hi.z += p3.x; hi.w += p3.y;
}

__device__ __forceinline__ void agg_core(const __half* __restrict__ t, const float* __restrict__ dinv,
                                         const int2* __restrict__ rowse, const int* __restrict__ csr,
                                         const float* __restrict__ bias, const float* __restrict__ gamma,
                                         const float* __restrict__ beta, const float* __restrict__ mean,
                                         const float* __restrict__ var,
                                         int i, int fl, float4& resL, float4& resH, float& di) {
    uint4 self = *(const uint4*)(t + (size_t)i * 64 + fl * 8);

    float4 lo = make_float4(0.f, 0.f, 0.f, 0.f);
    float4 hi = make_float4(0.f, 0.f, 0.f, 0.f);

    int2 se = rowse[i];
    int deg = se.y - se.x;
    int padEnd = se.x + ((deg + 7) & ~7);
    for (int e = se.x; e < padEnd; e += 8) {
        int s0 = csr[e + 0], s1 = csr[e + 1], s2 = csr[e + 2], s3 = csr[e + 3];
        int s4 = csr[e + 4], s5 = csr[e + 5], s6 = csr[e + 6], s7 = csr[e + 7];
        uint4 r0 = *(const uint4*)(t + (size_t)s0 * 64 + fl * 8);
        uint4 r1 = *(const uint4*)(t + (size_t)s1 * 64 + fl * 8);
        uint4 r2 = *(const uint4*)(t + (size_t)s2 * 64 + fl * 8);
        uint4 r3 = *(const uint4*)(t + (size_t)s3 * 64 + fl * 8);
        uint4 r4 = *(const uint4*)(t + (size_t)s4 * 64 + fl * 8);
        uint4 r5 = *(const uint4*)(t + (size_t)s5 * 64 + fl * 8);
        uint4 r6 = *(const uint4*)(t + (size_t)s6 * 64 + fl * 8);
        uint4 r7 = *(const uint4*)(t + (size_t)s7 * 64 + fl * 8);
        agg_add8(lo, hi, r0); agg_add8(lo, hi, r1); agg_add8(lo, hi, r2); agg_add8(lo, hi, r3);
        agg_add8(lo, hi, r4); agg_add8(lo, hi, r5); agg_add8(lo, hi, r6); agg_add8(lo, hi, r7);
    }

    float coef = 1.0f - (float)(padEnd - se.y);
    {
        float2 p0 = __half22float2(*(const __half2*)&self.x);
        float2 p1 = __half22float2(*(const __half2*)&self.y);
        float2 p2 = __half22float2(*(const __half2*)&self.z);
        float2 p3 = __half22float2(*(const __half2*)&self.w);
        lo.x += coef * p0.x; lo.y += coef * p0.y; lo.z += coef * p1.x; lo.w += coef * p1.y;
        hi.x += coef * p2.x; hi.y += coef * p2.y; hi.z += coef * p3.x; hi.w += coef * p3.y;
    }

    di = dinv[i];
    lo.x *= di; lo.y *= di; lo.z *= di; lo.w *= di;
    hi.x *= di; hi.y *= di; hi.z *= di; hi.w *= di;

    float4 bbL = ((const float4*)bias)[2 * fl],  bbH = ((const float4*)bias)[2 * fl + 1];
    float4 ggL = ((const float4*)gamma)[2 * fl], ggH = ((const float4*)gamma)[2 * fl + 1];
    float4 beL = ((const float4*)beta)[2 * fl],  beH = ((const float4*)beta)[2 * fl + 1];
    float4 mmL = ((const float4*)mean)[2 * fl],  mmH = ((const float4*)mean)[2 * fl + 1];
    float4 vvL = ((const float4*)var)[2 * fl],   vvH = ((const float4*)var)[2 * fl + 1];
    resL.x = fmaxf((lo.x + bbL.x - mmL.x) * (ggL.x * rsqrtf(vvL.x + EPS)) + beL.x, 0.f);
    resL.y = fmaxf((lo.y + bbL.y - mmL.y) * (ggL.y * rsqrtf(vvL.y + EPS)) + beL.y, 0.f);
    resL.z = fmaxf((lo.z + bbL.z - mmL.z) * (ggL.z * rsqrtf(vvL.z + EPS)) + beL.z, 0.f);
    resL.w = fmaxf((lo.w + bbL.w - mmL.w) * (ggL.w * rsqrtf(vvL.w + EPS)) + beL.w, 0.f);
    resH.x = fmaxf((hi.x + bbH.x - mmH.x) * (ggH.x * rsqrtf(vvH.x + EPS)) + beH.x, 0.f);
    resH.y = fmaxf((hi.y + bbH.y - mmH.y) * (ggH.y * rsqrtf(vvH.y + EPS)) + beH.y, 0.f);
    resH.z = fmaxf((hi.z + bbH.z - mmH.z) * (ggH.z * rsqrtf(vvH.z + EPS)) + beH.z, 0.f);
    resH.w = fmaxf((hi.w + bbH.w - mmH.w) * (ggH.w * rsqrtf(vvH.w + EPS)) + beH.w, 0.f);
}

// ---------------- phases 4/5: agg + BN/ReLU fused with next-layer GEMM ----------------
// W staged ONCE per block for the whole phase (was: once per 32-node tile).

__device__ __forceinline__ void agg_gemm_phase(char* smem, const GcnParams& P,
        const __half* tin, const float* W,
        const float* bias, const float* gamma, const float* beta,
        const float* mean, const float* var,
        __half* tout, int bid, int gdim) {
    const int KP = 72;
    _Float16* Ah = (_Float16*)smem;               // 4608 B (h tile, then out tile)
    _Float16* Wt = (_Float16*)(smem + 4608);      // 9216 B
    int*   nidS  = (int*)(smem + 13824);
    float* dvS   = (float*)(smem + 13952);
    int tid = threadIdx.x;
    for (int idx = tid; idx < 64 * 64; idx += 256) {
        int k = idx >> 6, c = idx & 63;
        Wt[c * KP + k] = (_Float16)W[idx];
    }
    __syncthreads();
    int wave = tid >> 6, lane = tid & 63;
    int g = lane >> 3, fl = lane & 7;
    int slotInBlk = wave * 8 + g;
    int m = lane & 15, quad = lane >> 4;
    int mrow = (wave & 1) * 16;
    int c0 = (wave >> 1) * 32;
    for (int tile = bid; tile < P.atiles; tile += gdim) {
        int slot = tile * 32 + slotInBlk;
        bool act = slot < P.N;
        if (act) {
            int i = P.perm[slot];
            float4 resL, resH; float di;
            agg_core(tin, P.dinv, P.rowse, P.csr, bias, gamma, beta, mean, var, i, fl, resL, resH, di);
            __half2 h0 = __floats2half2_rn(resL.x, resL.y);
            __half2 h1 = __floats2half2_rn(resL.z, resL.w);
            __half2 h2 = __floats2half2_rn(resH.x, resH.y);
            __half2 h3 = __floats2half2_rn(resH.z, resH.w);
            uint4 pk;
            pk.x = *(unsigned*)&h0; pk.y = *(unsigned*)&h1;
            pk.z = *(unsigned*)&h2; pk.w = *(unsigned*)&h3;
            *(uint4*)(Ah + slotInBlk * KP + fl * 8) = pk;
            if (fl == 0) { nidS[slotInBlk] = i; dvS[slotInBlk] = di; }
        } else {
            uint4 z = make_uint4(0, 0, 0, 0);
            *(uint4*)(Ah + slotInBlk * KP + fl * 8) = z;
            if (fl == 0) { nidS[slotInBlk] = 0; dvS[slotInBlk] = 0.f; }
        }
        __syncthreads();

        const _Float16* Aw = Ah + (mrow + m) * KP + quad * 8;
        const _Float16* Bw = Wt + (c0 + m) * KP + quad * 8;
        floatx4 acc0 = {0.f, 0.f, 0.f, 0.f}, acc1 = acc0;
#pragma unroll
        for (int k0 = 0; k0 < 64; k0 += 32) {
            half8 a  = *(const half8*)(Aw + k0);
            half8 b0 = *(const half8*)(Bw + k0);
            half8 b1 = *(const half8*)(Bw + 16 * KP + k0);
            acc0 = __builtin_amdgcn_mfma_f32_16x16x32_f16(a, b0, acc0, 0, 0, 0);
            acc1 = __builtin_amdgcn_mfma_f32_16x16x32_f16(a, b1, acc1, 0, 0, 0);
        }
        __syncthreads();   // all waves done reading Ah -> reuse as output tile

#pragma unroll
        for (int r = 0; r < 4; ++r) {
            int row = mrow + quad * 4 + r;
            float dv = dvS[row];
            Ah[row * KP + c0 + m]      = (_Float16)(acc0[r] * dv);
            Ah[row * KP + c0 + 16 + m] = (_Float16)(acc1[r] * dv);
        }
        __syncthreads();

        if (act) {
            int node = nidS[slotInBlk];
            uint4 v = *(const uint4*)(Ah + slotInBlk * KP + fl * 8);
            *(uint4*)(tout + (size_t)node * 64 + fl * 8) = v;
        }
        __syncthreads();   // protect Ah before next tile's agg writes
    }
}

// ---------------- phase 6: agg + BN/ReLU + classifier ----------------

__device__ __forceinline__ void agg_cls_phase(const GcnParams& P, int bid, int gdim) {
    int tid = threadIdx.x;
    int wave = tid >> 6, lane = tid & 63;
    int g = lane >> 3, fl = lane & 7;
    int slotInBlk = wave * 8 + g;
    const float* bias  = P.biases + 128;
    const float* gamma = P.gamma + 128;
    const float* beta  = P.beta + 128;
    const float* mean  = P.rmean + 128;
    const float* var   = P.rvar + 128;
    for (int tile = bid; tile < P.atiles; tile += gdim) {
        int slot = tile * 32 + slotInBlk;
        if (slot >= P.N) continue;
        int i = P.perm[slot];
        float4 resL, resH; float di;
        agg_core(P.tA, P.dinv, P.rowse, P.csr, bias, gamma, beta, mean, var, i, fl, resL, resH, di);
        const float4* cw = (const float4*)P.cls_w;
        float4 cwA = cw[4 * fl + 0], cwB = cw[4 * fl + 1], cwC = cw[4 * fl + 2], cwD = cw[4 * fl + 3];
        float c0 = resL.x * cwA.x + resL.y * cwA.z + resL.z * cwB.x + resL.w * cwB.z
                 + resH.x * cwC.x + resH.y * cwC.z + resH.z * cwD.x + resH.w * cwD.z;
        float c1 = resL.x * cwA.y + resL.y * cwA.w + resL.z * cwB.y + resL.w * cwB.w
                 + resH.x * cwC.y + resH.y * cwC.w + resH.z * cwD.y + resH.w * cwD.w;
        for (int off = 4; off > 0; off >>= 1) {
            c0 += __shfl_xor(c0, off);
            c1 += __shfl_xor(c1, off);
        }
        if (fl == 0) {
            P.out[(size_t)i * 2 + 0] = c0 + P.cls_b[0];
            P.out[(size_t)i * 2 + 1] = c1 + P.cls_b[1];
        }
    }
}

// ---------------- merged cooperative kernel ----------------

__global__ __launch_bounds__(256, 4) void gcn_merged(GcnParams P) {
    extern __shared__ char smem[];
    cg::grid_group grid = cg::this_grid();
    int bid = blockIdx.x, gdim = gridDim.x;

    for (int c = bid; c < P.na; c += gdim) bucketA_body(smem, P, c);
    grid.sync();
    for (int b = bid; b < P.nbuckets; b += gdim) bucketB_body(smem, P, b);
    grid.sync();
    gemm_phase(smem, P, bid, gdim);
    grid.sync();
#pragma unroll 1
    for (int l = 0; l < 2; ++l) {
        const __half* tin = l ? P.tB : P.tA;
        __half* tout      = l ? P.tA : P.tB;
        const float* W    = l ? P.w2 : P.w1;
        int off = l * 64;
        agg_gemm_phase(smem, P, tin, W, P.biases + off, P.gamma + off, P.beta + off,
                       P.rmean + off, P.rvar + off, tout, bid, gdim);
        grid.sync();
    }
    agg_cls_phase(P, bid, gdim);
}

// ---------------- launch ----------------

extern "C" void kernel_launch(void* const* d_in, const int* in_sizes, int n_in,
                              void* d_out, int out_size, void* d_ws, size_t ws_size,
                              hipStream_t stream) {
    GcnParams P;
    P.x      = (const float*)d_in[0];
    P.ei     = (const int*)d_in[1];
    P.w0     = (const float*)d_in[2];
    P.w1     = (const float*)d_in[3];
    P.w2     = (const float*)d_in[4];
    P.biases = (const float*)d_in[5];
    P.gamma  = (const float*)d_in[6];
    P.beta   = (const float*)d_in[7];
    P.rmean  = (const float*)d_in[8];
    P.rvar   = (const float*)d_in[9];
    P.cls_w  = (const float*)d_in[10];
    P.cls_b  = (const float*)d_in[11];
    P.out    = (float*)d_out;

    const int IN_ = 128, H = 64;
    int N = in_sizes[0] / IN_;   // 100000
    int E = in_sizes[1] / 2;     // 1200000

    char* p = (char*)d_ws;
    auto carve = [&](size_t bytes) { void* q = (void*)p; p += (bytes + 255) & ~(size_t)255; return q; };
    P.dinv        = (float*)carve((size_t)N * 4);
    P.rowse       = (int2*)carve((size_t)N * 8);
    P.bucket_fill = (int*)carve((size_t)NBKT_MAX * 4);
    P.perm        = (int*)carve((size_t)N * 4);
    P.tmp         = (unsigned*)carve((size_t)NBKT_MAX * BCAP * 4);
    P.csr         = (int*)carve((size_t)NBKT_MAX * BCSR * 4);
    P.tA          = (__half*)carve((size_t)N * H * 2);
    P.tB          = (__half*)carve((size_t)N * H * 2);

    P.N = N; P.E = E;
    P.na = (E + ACHUNK - 1) / ACHUNK;           // 586
    P.nbuckets = (N + 255) >> 8;                // 391
    P.gtiles = (N + 63) / 64;                   // 1563
    P.atiles = (N + 31) / 32;                   // 3125

    hipMemsetAsync(P.bucket_fill, 0, (size_t)NBKT_MAX * 4, stream);

    static int s_grid = 0;
    if (s_grid == 0) {
        int maxb = 0;
        hipOccupancyMaxActiveBlocksPerMultiprocessor(&maxb, (const void*)gcn_merged, 256, SMEM_BYTES);
        if (maxb < 1) maxb = 1;
        int dev = 0;
        hipGetDevice(&dev);
        int nCU = 0;
        hipDeviceGetAttribute(&nCU, hipDeviceAttributeMultiprocessorCount, dev);
        if (nCU <= 0) nCU = 256;
        s_grid = maxb * nCU;
    }

    void* kargs[] = { (void*)&P };
    hipLaunchCooperativeKernel((const void*)gcn_merged, dim3(s_grid), dim3(256), kargs,
                               SMEM_BYTES, stream);
}

// Round 5
// 241.991 us; speedup vs baseline: 2.5303x; 2.5303x over previous
//
#include <hip/hip_runtime.h>
#include <hip/hip_fp16.h>

#define EPS 1e-5f
#define ABITS 9           // 512 nodes per target-bucket
#define ACHUNK 4096       // edges per block in bucket pass A
#define BCAP 8192         // tmp capacity per bucket (avg ~6150, >26 sigma margin)
#define BCSR 12288        // padded csr capacity per bucket (<= BCAP + 512*7)
#define CSHIFT 13         // src-chunk = src >> 13 (1 MB of t per chunk)
#define NCHUNK 16
// tmp entry packing: (dstOff << 17) | src  — requires N <= 131072 (N=100000 ok)

typedef _Float16 half8 __attribute__((ext_vector_type(8)));
typedef float floatx4 __attribute__((ext_vector_type(4)));

// ---------------- graph prep (2 kernels, padded buckets, no global scan) ----------------

// A: single pass over ei — stage chunk in LDS, LDS histogram, reserve bucket runs,
// scatter packed entries from LDS (ei read once, 9.6 MB total).
__global__ __launch_bounds__(256) void bucketA_kernel(const int* __restrict__ ei, int E,
                                                      int* __restrict__ bucket_fill, unsigned* __restrict__ tmp) {
    __shared__ int2 edg[ACHUNK];            // 32 KB
    __shared__ int hist[256], lbase[256], lcur[256];
    int t = threadIdx.x;
    hist[t] = 0; lcur[t] = 0;
    __syncthreads();
    int e0 = blockIdx.x * ACHUNK;
    int e1 = e0 + ACHUNK; if (e1 > E) e1 = E;
    int ne = e1 - e0;
    for (int idx = t; idx < ne; idx += 256) {
        int r = ei[e0 + idx], c = ei[E + e0 + idx];
        edg[idx] = make_int2(r, c);
        atomicAdd(&hist[c >> ABITS], 1);
    }
    __syncthreads();
    int h = hist[t];
    if (h) lbase[t] = atomicAdd(&bucket_fill[t], h);
    __syncthreads();
    for (int idx = t; idx < ne; idx += 256) {
        int2 e = edg[idx];
        int b = e.y >> ABITS;
        int l = atomicAdd(&lcur[b], 1);
        tmp[(size_t)b * BCAP + lbase[b] + l] = ((unsigned)(e.y & 511) << 17) | (unsigned)e.x;
    }
}

// B: per bucket — stage packed edges in LDS, count (dst,chunk), scan PADDED counts,
// write rowse(start, start+deg) + dinv, place srcs grouped by src-chunk, then pad
// each node's list to a multiple of 8 with src=i (agg corrects with (1-k)*t[i]).
// Also histograms nodes by iteration-class k = ceil(deg/8) into classCnt (for perm).
__global__ __launch_bounds__(256) void bucketB_kernel(const unsigned* __restrict__ tmp,
                                                      const int* __restrict__ bucket_fill,
                                                      int2* __restrict__ rowse, float* __restrict__ dinv,
                                                      int* __restrict__ csr, int* __restrict__ classCnt, int n) {
    __shared__ unsigned edg[BCAP];          // 32 KB (packed)
    __shared__ int cnt2[512 * NCHUNK];      // 32 KB: counts -> seg cursors
    __shared__ int ps[256];
    __shared__ int ccnt[16];
    int b = blockIdx.x, t = threadIdx.x;
    int n0 = b << ABITS;
    int cntN = n - n0; if (cntN > 512) cntN = 512;
    int ne = bucket_fill[b]; if (ne > BCAP) ne = BCAP;
    int base = b * BCAP;
    int cbase = b * BCSR;
    if (t < 16) ccnt[t] = 0;
    for (int i = t; i < 512 * NCHUNK; i += 256) cnt2[i] = 0;
    for (int idx = t; idx < ne; idx += 256) edg[idx] = tmp[(size_t)base + idx];
    __syncthreads();
    for (int idx = t; idx < ne; idx += 256) {
        unsigned e = edg[idx];
        int dstOff = e >> 17, src = e & 0x1FFFF;
        atomicAdd(&cnt2[dstOff * NCHUNK + (src >> CSHIFT)], 1);
    }
    __syncthreads();
    int c0 = 0, c1 = 0;
#pragma unroll
    for (int c = 0; c < NCHUNK; ++c) {
        c0 += cnt2[(2 * t) * NCHUNK + c];
        c1 += cnt2[(2 * t + 1) * NCHUNK + c];
    }
    // degree-class histogram (iterations in agg = ceil(deg/8))
    {
        int k0c = (c0 + 7) >> 3; if (k0c > 15) k0c = 15;
        int k1c = (c1 + 7) >> 3; if (k1c > 15) k1c = 15;
        if (2 * t < cntN) atomicAdd(&ccnt[k0c], 1);
        if (2 * t + 1 < cntN) atomicAdd(&ccnt[k1c], 1);
    }
    int p0 = (c0 + 7) & ~7, p1 = (c1 + 7) & ~7;   // padded lengths
    int s = p0 + p1;
    ps[t] = s;
    __syncthreads();
    for (int off = 1; off < 256; off <<= 1) {
        int u = (t >= off) ? ps[t - off] : 0;
        __syncthreads();
        ps[t] += u;
        __syncthreads();
    }
    int excl = ps[t] - s;
    int st0 = cbase + excl, st1 = cbase + excl + p0;
    if (2 * t < cntN) {
        rowse[n0 + 2 * t] = make_int2(st0, st0 + c0);
        dinv[n0 + 2 * t] = rsqrtf((float)(c0 + 1));
    }
    if (2 * t + 1 < cntN) {
        rowse[n0 + 2 * t + 1] = make_int2(st1, st1 + c1);
        dinv[n0 + 2 * t + 1] = rsqrtf((float)(c1 + 1));
    }
    // pads: fill [start+deg, start+pdeg) with own node index (self row, L2-hot)
    if (2 * t < cntN)
        for (int j = c0; j < p0; ++j) csr[st0 + j] = n0 + 2 * t;
    if (2 * t + 1 < cntN)
        for (int j = c1; j < p1; ++j) csr[st1 + j] = n0 + 2 * t + 1;
    // counts -> per-(node,chunk) segment cursors
    int run = st0;
#pragma unroll
    for (int c = 0; c < NCHUNK; ++c) {
        int v = cnt2[(2 * t) * NCHUNK + c];
        cnt2[(2 * t) * NCHUNK + c] = run;
        run += v;
    }
    run = st1;
#pragma unroll
    for (int c = 0; c < NCHUNK; ++c) {
        int v = cnt2[(2 * t + 1) * NCHUNK + c];
        cnt2[(2 * t + 1) * NCHUNK + c] = run;
        run += v;
    }
    __syncthreads();
    for (int idx = t; idx < ne; idx += 256) {
        unsigned e = edg[idx];
        int dstOff = e >> 17, src = e & 0x1FFFF;
        int key = dstOff * NCHUNK + (src >> CSHIFT);
        int pos = atomicAdd(&cnt2[key], 1);
        csr[pos] = src;
    }
    __syncthreads();
    if (t < 16) atomicAdd(&classCnt[t], ccnt[t]);
}

// perm: stable-ish two-level counting sort of nodes by iteration-class.
// Groups of 8 consecutive perm-slots then share a degree class -> no wave divergence.
__global__ __launch_bounds__(256) void perm_kernel(const int2* __restrict__ rowse,
                                                   const int* __restrict__ classCnt,
                                                   int* __restrict__ classCur,
                                                   int* __restrict__ perm, int n) {
    __shared__ int lcnt[16], lbase[16], gbase[16];
    int t = threadIdx.x;
    if (t < 16) lcnt[t] = 0;
    __syncthreads();
    int i = blockIdx.x * 256 + t;
    int k = 0, lrank = 0;
    if (i < n) {
        int2 se = rowse[i];
        int deg = se.y - se.x;
        k = (deg + 7) >> 3; if (k > 15) k = 15;
        lrank = atomicAdd(&lcnt[k], 1);
    }
    __syncthreads();
    if (t < 16) {
        lbase[t] = atomicAdd(&classCur[t], lcnt[t]);
        int bsum = 0;
        for (int j = 0; j < t; ++j) bsum += classCnt[j];
        gbase[t] = bsum;
    }
    __syncthreads();
    if (i < n) perm[gbase[k] + lbase[k] + lrank] = i;
}

// ---------------- dense GEMM via MFMA: [n,K] @ [K,64] -> dinv[row] * result (f16) ----------------
// (used for layer 0 only; layers 1/2 GEMMs are fused into the agg epilogue)

template <int K, typename TIN>
__global__ __launch_bounds__(256) void gemm_kernel(const TIN* __restrict__ A, const float* __restrict__ W,
                                                   const float* __restrict__ dinv, __half* __restrict__ out, int n) {
    const int KP = K + 8;
    __shared__ _Float16 Ah[64 * (K + 8)];
    __shared__ _Float16 Wt[64 * (K + 8)];
    int tid = threadIdx.x;

    for (int idx = tid; idx < K * 64; idx += 256) {
        int k = idx >> 6, c = idx & 63;
        Wt[c * KP + k] = (_Float16)W[idx];
    }
    int row0 = blockIdx.x * 64;
    const TIN* Ab = A + (size_t)row0 * K;
    int limit = (n - row0) * K; if (limit > 64 * K) limit = 64 * K;

    if constexpr (sizeof(TIN) == 4) {   // float input
        for (int f = tid * 4; f < 64 * K; f += 1024) {
            float4 v = make_float4(0.f, 0.f, 0.f, 0.f);
            if (f + 3 < limit) {
                v = *(const float4*)((const float*)Ab + f);
            } else {
                if (f + 0 < limit) v.x = ((const float*)Ab)[f + 0];
                if (f + 1 < limit) v.y = ((const float*)Ab)[f + 1];
                if (f + 2 < limit) v.z = ((const float*)Ab)[f + 2];
            }
            int row = f / K, k = f % K;
            _Float16* dst = Ah + row * KP + k;
            dst[0] = (_Float16)v.x; dst[1] = (_Float16)v.y;
            dst[2] = (_Float16)v.z; dst[3] = (_Float16)v.w;
        }
    } else {                            // fp16 input: straight copy
        for (int f = tid * 8; f < 64 * K; f += 2048) {
            uint4 v = make_uint4(0, 0, 0, 0);
            if (f + 7 < limit) {
                v = *(const uint4*)((const __half*)Ab + f);
            } else {
                const __half* hp = (const __half*)Ab;
                __half tmp8[8];
                for (int j = 0; j < 8; ++j) tmp8[j] = (f + j < limit) ? hp[f + j] : __half(0);
                v = *(const uint4*)tmp8;
            }
            int row = f / K, k = f % K;
            *(uint4*)(Ah + row * KP + k) = v;
        }
    }
    __syncthreads();

    int w = tid >> 6, lane = tid & 63;
    int m = lane & 15, quad = lane >> 4;
    const _Float16* Aw = Ah + (size_t)(w * 16 + m) * KP + quad * 8;
    const _Float16* Bw = Wt + (size_t)m * KP + quad * 8;

    floatx4 acc0 = {0.f, 0.f, 0.f, 0.f}, acc1 = acc0, acc2 = acc0, acc3 = acc0;
    for (int k0 = 0; k0 < K; k0 += 32) {
        half8 a  = *(const half8*)(Aw + k0);
        half8 b0 = *(const half8*)(Bw + 0 * 16 * KP + k0);
        half8 b1 = *(const half8*)(Bw + 1 * 16 * KP + k0);
        half8 b2 = *(const half8*)(Bw + 2 * 16 * KP + k0);
        half8 b3 = *(const half8*)(Bw + 3 * 16 * KP + k0);
        acc0 = __builtin_amdgcn_mfma_f32_16x16x32_f16(a, b0, acc0, 0, 0, 0);
        acc1 = __builtin_amdgcn_mfma_f32_16x16x32_f16(a, b1, acc1, 0, 0, 0);
        acc2 = __builtin_amdgcn_mfma_f32_16x16x32_f16(a, b2, acc2, 0, 0, 0);
        acc3 = __builtin_amdgcn_mfma_f32_16x16x32_f16(a, b3, acc3, 0, 0, 0);
    }

    int rbase = row0 + w * 16 + quad * 4;
#pragma unroll
    for (int r = 0; r < 4; ++r) {
        int row = rbase + r;
        if (row < n) {
            float dv = dinv[row];
            __half* o = out + (size_t)row * 64 + m;
            o[0]  = __float2half(acc0[r] * dv);
            o[16] = __float2half(acc1[r] * dv);
            o[32] = __float2half(acc2[r] * dv);
            o[48] = __float2half(acc3[r] * dv);
        }
    }
}

// ---------------- aggregation + bias + BN(eval) + ReLU ----------------
// Full-row gather (8 lanes x 16 B = one 128 B line/edge). Wave = 8 independent
// 8-lane groups, one node per group. Nodes globally class-sorted via perm so
// the 8 groups of a wave run the same iteration count. Gather loop software-
// pipelined: next csr block prefetched before current gathers are consumed,
// breaking the serial csr->gather latency chain.

__device__ __forceinline__ void agg_add8(float4& lo, float4& hi, uint4 raw) {
    float2 p0 = __half22float2(*(const __half2*)&raw.x);
    float2 p1 = __half22float2(*(const __half2*)&raw.y);
    float2 p2 = __half22float2(*(const __half2*)&raw.z);
    float2 p3 = __half22float2(*(const __half2*)&raw.w);
    lo.x += p0.x; lo.y += p0.y; lo.z += p1.x; lo.w += p1.y;
    hi.x += p2.x; hi.y += p2.y; hi.z += p3.x; hi.w += p3.y;
}

// Core aggregation for one node i; returns BN/ReLU'd features in resL/resH and dinv in di.
__device__ __forceinline__ void agg_core(const __half* __restrict__ t, const float* __restrict__ dinv,
                                         const int2* __restrict__ rowse, const int* __restrict__ csr,
                                         const float* __restrict__ bias, const float* __restrict__ gamma,
                                         const float* __restrict__ beta, const float* __restrict__ mean,
                                         const float* __restrict__ var,
                                         int i, int fl, float4& resL, float4& resH, float& di) {
    int2 se = rowse[i];
    // self row (prefetch; also the pad-correction operand)
    uint4 self = *(const uint4*)(t + (size_t)i * 64 + fl * 8);

    float4 lo = make_float4(0.f, 0.f, 0.f, 0.f);
    float4 hi = make_float4(0.f, 0.f, 0.f, 0.f);

    int deg = se.y - se.x;
    int padEnd = se.x + ((deg + 7) & ~7);
    // pipelined gather: s0..s7 hold the csr block for the CURRENT iteration,
    // prefetched one iteration ahead.
    int s0, s1, s2, s3, s4, s5, s6, s7;
    {
        const int* cp = csr + se.x;
        s0 = cp[0]; s1 = cp[1]; s2 = cp[2]; s3 = cp[3];
        s4 = cp[4]; s5 = cp[5]; s6 = cp[6]; s7 = cp[7];
    }
    for (int e = se.x; e < padEnd; e += 8) {
        int t0 = s0, t1 = s1, t2 = s2, t3 = s3, t4 = s4, t5 = s5, t6 = s6, t7 = s7;
        if (e + 8 < padEnd) {
            const int* cp = csr + e + 8;
            s0 = cp[0]; s1 = cp[1]; s2 = cp[2]; s3 = cp[3];
            s4 = cp[4]; s5 = cp[5]; s6 = cp[6]; s7 = cp[7];
        }
        uint4 r0 = *(const uint4*)(t + (size_t)t0 * 64 + fl * 8);
        uint4 r1 = *(const uint4*)(t + (size_t)t1 * 64 + fl * 8);
        uint4 r2 = *(const uint4*)(t + (size_t)t2 * 64 + fl * 8);
        uint4 r3 = *(const uint4*)(t + (size_t)t3 * 64 + fl * 8);
        uint4 r4 = *(const uint4*)(t + (size_t)t4 * 64 + fl * 8);
        uint4 r5 = *(const uint4*)(t + (size_t)t5 * 64 + fl * 8);
        uint4 r6 = *(const uint4*)(t + (size_t)t6 * 64 + fl * 8);
        uint4 r7 = *(const uint4*)(t + (size_t)t7 * 64 + fl * 8);
        agg_add8(lo, hi, r0); agg_add8(lo, hi, r1); agg_add8(lo, hi, r2); agg_add8(lo, hi, r3);
        agg_add8(lo, hi, r4); agg_add8(lo, hi, r5); agg_add8(lo, hi, r6); agg_add8(lo, hi, r7);
    }

    // pad correction: padSum included k copies of t[i]; want edges + 1*t[i]
    float coef = 1.0f - (float)(padEnd - se.y);
    {
        float2 p0 = __half22float2(*(const __half2*)&self.x);
        float2 p1 = __half22float2(*(const __half2*)&self.y);
        float2 p2 = __half22float2(*(const __half2*)&self.z);
        float2 p3 = __half22float2(*(const __half2*)&self.w);
        lo.x += coef * p0.x; lo.y += coef * p0.y; lo.z += coef * p1.x; lo.w += coef * p1.y;
        hi.x += coef * p2.x; hi.y += coef * p2.y; hi.z += coef * p3.x; hi.w += coef * p3.y;
    }

    di = dinv[i];
    lo.x *= di; lo.y *= di; lo.z *= di; lo.w *= di;
    hi.x *= di; hi.y *= di; hi.z *= di; hi.w *= di;

    float4 bbL = ((const float4*)bias)[2 * fl],  bbH = ((const float4*)bias)[2 * fl + 1];
    float4 ggL = ((const float4*)gamma)[2 * fl], ggH = ((const float4*)gamma)[2 * fl + 1];
    float4 beL = ((const float4*)beta)[2 * fl],  beH = ((const float4*)beta)[2 * fl + 1];
    float4 mmL = ((const float4*)mean)[2 * fl],  mmH = ((const float4*)mean)[2 * fl + 1];
    float4 vvL = ((const float4*)var)[2 * fl],   vvH = ((const float4*)var)[2 * fl + 1];
    resL.x = fmaxf((lo.x + bbL.x - mmL.x) * (ggL.x * rsqrtf(vvL.x + EPS)) + beL.x, 0.f);
    resL.y = fmaxf((lo.y + bbL.y - mmL.y) * (ggL.y * rsqrtf(vvL.y + EPS)) + beL.y, 0.f);
    resL.z = fmaxf((lo.z + bbL.z - mmL.z) * (ggL.z * rsqrtf(vvL.z + EPS)) + beL.z, 0.f);
    resL.w = fmaxf((lo.w + bbL.w - mmL.w) * (ggL.w * rsqrtf(vvL.w + EPS)) + beL.w, 0.f);
    resH.x = fmaxf((hi.x + bbH.x - mmH.x) * (ggH.x * rsqrtf(vvH.x + EPS)) + beH.x, 0.f);
    resH.y = fmaxf((hi.y + bbH.y - mmH.y) * (ggH.y * rsqrtf(vvH.y + EPS)) + beH.y, 0.f);
    resH.z = fmaxf((hi.z + bbH.z - mmH.z) * (ggH.z * rsqrtf(vvH.z + EPS)) + beH.z, 0.f);
    resH.w = fmaxf((hi.w + bbH.w - mmH.w) * (ggH.w * rsqrtf(vvH.w + EPS)) + beH.w, 0.f);
}

// Fused: aggregation(+BN/ReLU) of 32 nodes -> LDS A-tile -> [32x64]@[64x64] MFMA
// -> dinv-scaled fp16 scatter-write of next layer's t rows.
// __launch_bounds__(256,6): 24 waves/CU (VGPR cap ~85 > ~65 needed) — latency hiding.
__global__ __launch_bounds__(256, 6) void agg_gemm_kernel(
        const __half* __restrict__ t, const float* __restrict__ dinv,
        const int2* __restrict__ rowse, const int* __restrict__ csr,
        const int* __restrict__ perm,
        const float* __restrict__ bias, const float* __restrict__ gamma,
        const float* __restrict__ beta, const float* __restrict__ mean,
        const float* __restrict__ var,
        const float* __restrict__ W,          // [64][64] row-major (k, c)
        __half* __restrict__ tout, int n) {
    const int KP = 72;
    __shared__ _Float16 Ah[32 * 72];          // 4.5 KB  (post-BN/ReLU h, fp16)
    __shared__ _Float16 Wt[64 * 72];          // 9 KB    (W transposed)
    __shared__ int   nidS[32];
    __shared__ float dvS[32];

    int tid = threadIdx.x;
    // stage W transposed (L2-broadcast-hot, 16 KB)
    for (int idx = tid; idx < 64 * 64; idx += 256) {
        int k = idx >> 6, c = idx & 63;
        Wt[c * KP + k] = (_Float16)W[idx];
    }

    int wave = tid >> 6, lane = tid & 63;
    int g = lane >> 3, fl = lane & 7;
    int slotInBlk = wave * 8 + g;
    int slot = blockIdx.x * 32 + slotInBlk;
    bool act = slot < n;

    if (act) {
        int i = perm[slot];
        float4 resL, resH; float di;
        agg_core(t, dinv, rowse, csr, bias, gamma, beta, mean, var, i, fl, resL, resH, di);
        __half2 h0 = __floats2half2_rn(resL.x, resL.y);
        __half2 h1 = __floats2half2_rn(resL.z, resL.w);
        __half2 h2 = __floats2half2_rn(resH.x, resH.y);
        __half2 h3 = __floats2half2_rn(resH.z, resH.w);
        uint4 pk;
        pk.x = *(unsigned*)&h0; pk.y = *(unsigned*)&h1;
        pk.z = *(unsigned*)&h2; pk.w = *(unsigned*)&h3;
        *(uint4*)(Ah + slotInBlk * KP + fl * 8) = pk;
        if (fl == 0) { nidS[slotInBlk] = i; dvS[slotInBlk] = di; }
    } else {
        uint4 z = make_uint4(0, 0, 0, 0);
        *(uint4*)(Ah + slotInBlk * KP + fl * 8) = z;
        if (fl == 0) { nidS[slotInBlk] = 0; dvS[slotInBlk] = 0.f; }
    }
    __syncthreads();

    // MFMA: wave w covers rows (w&1)*16..+15, cols (w>>1)*32..+31
    int m = lane & 15, quad = lane >> 4;
    int mrow = (wave & 1) * 16;
    int c0 = (wave >> 1) * 32;
    const _Float16* Aw = Ah + (mrow + m) * KP + quad * 8;
    const _Float16* Bw = Wt + (c0 + m) * KP + quad * 8;

    floatx4 acc0 = {0.f, 0.f, 0.f, 0.f}, acc1 = acc0;
#pragma unroll
    for (int k0 = 0; k0 < 64; k0 += 32) {
        half8 a  = *(const half8*)(Aw + k0);
        half8 b0 = *(const half8*)(Bw + k0);
        half8 b1 = *(const half8*)(Bw + 16 * KP + k0);
        acc0 = __builtin_amdgcn_mfma_f32_16x16x32_f16(a, b0, acc0, 0, 0, 0);
        acc1 = __builtin_amdgcn_mfma_f32_16x16x32_f16(a, b1, acc1, 0, 0, 0);
    }

#pragma unroll
    for (int r = 0; r < 4; ++r) {
        int row = mrow + quad * 4 + r;
        if (blockIdx.x * 32 + row < n) {
            int node = nidS[row];
            float dv = dvS[row];
            __half* o = tout + (size_t)node * 64;
            o[c0 + m]      = __float2half(acc0[r] * dv);
            o[c0 + 16 + m] = __float2half(acc1[r] * dv);
        }
    }
}

// Final layer: aggregation(+BN/ReLU) fused with the 64->2 classifier.
__global__ __launch_bounds__(256, 6) void agg_cls_kernel(
        const __half* __restrict__ t, const float* __restrict__ dinv,
        const int2* __restrict__ rowse, const int* __restrict__ csr,
        const int* __restrict__ perm,
        const float* __restrict__ bias, const float* __restrict__ gamma,
        const float* __restrict__ beta, const float* __restrict__ mean,
        const float* __restrict__ var,
        float* __restrict__ fout,
        const float* __restrict__ cls_w, const float* __restrict__ cls_b,
        int n) {
    int wave = threadIdx.x >> 6;
    int lane = threadIdx.x & 63;
    int g = lane >> 3;
    int fl = lane & 7;
    int slot = (blockIdx.x * (blockDim.x >> 6) + wave) * 8 + g;
    if (slot >= n) return;
    int i = perm[slot];

    float4 resL, resH; float di;
    agg_core(t, dinv, rowse, csr, bias, gamma, beta, mean, var, i, fl, resL, resH, di);

    const float4* cw = (const float4*)cls_w;
    float4 cwA = cw[4 * fl + 0], cwB = cw[4 * fl + 1], cwC = cw[4 * fl + 2], cwD = cw[4 * fl + 3];
    float c0 = resL.x * cwA.x + resL.y * cwA.z + resL.z * cwB.x + resL.w * cwB.z
             + resH.x * cwC.x + resH.y * cwC.z + resH.z * cwD.x + resH.w * cwD.z;
    float c1 = resL.x * cwA.y + resL.y * cwA.w + resL.z * cwB.y + resL.w * cwB.w
             + resH.x * cwC.y + resH.y * cwC.w + resH.z * cwD.y + resH.w * cwD.w;
    for (int off = 4; off > 0; off >>= 1) {
        c0 += __shfl_xor(c0, off);
        c1 += __shfl_xor(c1, off);
    }
    if (fl == 0) {
        fout[(size_t)i * 2 + 0] = c0 + cls_b[0];
        fout[(size_t)i * 2 + 1] = c1 + cls_b[1];
    }
}

// ---------------- launch ----------------

extern "C" void kernel_launch(void* const* d_in, const int* in_sizes, int n_in,
                              void* d_out, int out_size, void* d_ws, size_t ws_size,
                              hipStream_t stream) {
    const float* x      = (const float*)d_in[0];
    const int*   ei     = (const int*)d_in[1];
    const float* w0     = (const float*)d_in[2];
    const float* w1     = (const float*)d_in[3];
    const float* w2     = (const float*)d_in[4];
    const float* biases = (const float*)d_in[5];
    const float* gamma  = (const float*)d_in[6];
    const float* beta   = (const float*)d_in[7];
    const float* rmean  = (const float*)d_in[8];
    const float* rvar   = (const float*)d_in[9];
    const float* cls_w  = (const float*)d_in[10];
    const float* cls_b  = (const float*)d_in[11];
    float* out = (float*)d_out;

    const int IN = 128, H = 64;
    const int N = in_sizes[0] / IN;   // 100000
    const int E = in_sizes[1] / 2;    // 1200000

    char* p = (char*)d_ws;
    auto carve = [&](size_t bytes) { void* q = (void*)p; p += (bytes + 255) & ~(size_t)255; return q; };
    float* dinv    = (float*)carve((size_t)N * 4);
    int2*  rowse   = (int2*)carve((size_t)N * 8);
    int*   meta    = (int*)carve((size_t)288 * 4);   // bucket_fill[256] | classCnt[16] | classCur[16]
    int*   perm    = (int*)carve((size_t)N * 4);
    unsigned* tmp  = (unsigned*)carve((size_t)256 * BCAP * 4);
    int*   csr     = (int*)carve((size_t)256 * BCSR * 4);
    __half* tA     = (__half*)carve((size_t)N * H * 2);
    __half* tB     = (__half*)carve((size_t)N * H * 2);

    int* bucket_fill = meta;
    int* classCnt    = meta + 256;
    int* classCur    = meta + 272;

    int nbuckets = (N + (1 << ABITS) - 1) >> ABITS;   // 196 for N=100000
    int na = (E + ACHUNK - 1) / ACHUNK;               // 293

    hipMemsetAsync(meta, 0, (size_t)288 * 4, stream);
    bucketA_kernel<<<na, 256, 0, stream>>>(ei, E, bucket_fill, tmp);
    bucketB_kernel<<<nbuckets, 256, 0, stream>>>(tmp, bucket_fill, rowse, dinv, csr, classCnt, N);
    perm_kernel<<<(N + 255) / 256, 256, 0, stream>>>(rowse, classCnt, classCur, perm, N);

    int gemm_grid = (N + 63) / 64;
    int agg_grid  = (N + 31) / 32;   // 32 nodes per block (4 waves x 8 groups)

    // layer 0
    gemm_kernel<128, float><<<gemm_grid, 256, 0, stream>>>(x, w0, dinv, tA, N);
    agg_gemm_kernel<<<agg_grid, 256, 0, stream>>>(tA, dinv, rowse, csr, perm,
        biases + 0, gamma + 0, beta + 0, rmean + 0, rvar + 0, w1, tB, N);
    agg_gemm_kernel<<<agg_grid, 256, 0, stream>>>(tB, dinv, rowse, csr, perm,
        biases + H, gamma + H, beta + H, rmean + H, rvar + H, w2, tA, N);
    agg_cls_kernel<<<agg_grid, 256, 0, stream>>>(tA, dinv, rowse, csr, perm,
        biases + 2 * H, gamma + 2 * H, beta + 2 * H, rmean + 2 * H, rvar + 2 * H,
        out, cls_w, cls_b, N);
}